// Round 3
// baseline (1632.299 us; speedup 1.0000x reference)
//
#include <hip/hip_runtime.h>
#include <hip/hip_bf16.h>
#include <math.h>

#define PI_F 3.14159265358979323846f
#define R0_F 5.0f

// ---------------------------------------------------------------------------
// Workspace layout (float):
//   P[n][816]  : per-node input projections
//       [0,48)    Pa[k][r]      k=0:pa000,1:pa011,2:pa022           (k*16+r)
//       [48,240)  Pv[k][r][i]   k=0:pv101,1:pv110,2:pv112,3:pv121   (48+k*48+3r+i)
//       [240,816) Pd[k][r][ij]  k=0:pd202,1:pd211,2:pd220,3:pd222   (240+k*144+9r+ij)
//   M[n][528]  : per-node accumulated messages
//       [0,48)    rank-space a messages  m_a[k][r]
//       [48,240)  rank-space v messages  m_v[k][r][c]
//       [240,528) channel-space d psi    psi_d[d][ij]
// ---------------------------------------------------------------------------

// ------------------- K1: per-node input projections ------------------------
__global__ __launch_bounds__(256) void node_proj_kernel(
    const float* __restrict__ x_a, const float* __restrict__ x_v, const float* __restrict__ x_d,
    const float* __restrict__ W1_a, const float* __restrict__ W1_v, const float* __restrict__ W1_d,
    float* __restrict__ P)
{
  int n = blockIdx.x, tid = threadIdx.x;
  __shared__ float sx[608];  // xa[128] | xv[192] | xd[288]
  {
    const size_t na = (size_t)n * 128, nv = (size_t)n * 192, nd = (size_t)n * 288;
    if (tid < 128) sx[tid] = x_a[na + tid];
    if (tid < 192) sx[128 + tid] = x_v[nv + tid];
    for (int i = tid; i < 288; i += 256) sx[320 + i] = x_d[nd + i];
  }
  __syncthreads();
  float* Pn = P + (size_t)n * 816;
  for (int o = tid; o < 816; o += 256) {
    float acc = 0.0f;
    if (o < 48) {
      int k = o >> 4, r = o & 15;
      const float* w = W1_a + k * 2048 + r * 128;
      for (int c = 0; c < 128; c++) acc += w[c] * sx[c];
    } else if (o < 240) {
      int m = o - 48; int k = m / 48, rr = m % 48, r = rr / 3, i = rr % 3;
      const float* w = W1_v + k * 1024 + r * 64;
      for (int d = 0; d < 64; d++) acc += w[d] * sx[128 + 3 * d + i];
    } else {
      int m = o - 240; int k = m / 144, rr = m % 144, r = rr / 9, ij = rr % 9;
      const float* w = W1_d + k * 512 + r * 32;
      for (int d = 0; d < 32; d++) acc += w[d] * sx[320 + 9 * d + ij];
    }
    Pn[o] = acc;
  }
}

static __device__ __forceinline__ float dot4(float4 a, float4 b) {
  return a.x * b.x + a.y * b.y + a.z * b.z + a.w * b.w;
}

// ------------------- K2: per-edge messages (one wave per edge) --------------
__global__ __launch_bounds__(64, 4) void edge_kernel(
    const float* __restrict__ r_ij, const int* __restrict__ src, const int* __restrict__ dst,
    const float* __restrict__ P, float* __restrict__ M,
    const float* __restrict__ W2, const float* __restrict__ Wo_d)
{
  int e = blockIdx.x, lane = threadIdx.x;
  // LDS: sP[816] | sq[176] | sT0[16] | sT1[48] | sT3[48] | sT2[144]
  __shared__ __align__(16) float smem[816 + 176 + 16 + 48 + 48 + 144];
  float* sP  = smem;
  float* sq  = smem + 816;
  float* sT0 = smem + 992;
  float* sT1 = smem + 1008;   // [i*16 + r]
  float* sT3 = smem + 1056;   // [i*16 + r]
  float* sT2 = smem + 1104;   // [ij*16 + r]

  float r0 = r_ij[3 * (size_t)e + 0];
  float r1 = r_ij[3 * (size_t)e + 1];
  float r2 = r_ij[3 * (size_t)e + 2];
  float x_sq = (r0 * r0 + r1 * r1 + r2 * r2) * (1.0f / R0_F);
  float env = 1.0f - x_sq;
  if (env <= 0.0f) return;  // envelope kills every message (uniform across wave)

  int s_n = src[e], d_n = dst[e];

  // rv = tens_sigmoid_vec(r * 17/5)
  float v0 = r0 * (17.0f / R0_F), v1 = r1 * (17.0f / R0_F), v2 = r2 * (17.0f / R0_F);
  float nn = sqrtf(v0 * v0 + v1 * v1 + v2 * v2);
  float sig = 2.0f / (1.0f + expf(-nn)) - 1.0f;
  float sc = sig / (nn + 1e-6f);
  float rv0 = v0 * sc, rv1 = v1 * sc, rv2 = v2 * sc;
  float rva[3] = {rv0, rv1, rv2};

  // radial basis via Chebyshev recurrence: cos(k*th), th = pi*sqrt(x_sq)
  float rad[8];
  {
    float c1 = cosf(PI_F * sqrtf(x_sq));
    float two_c1 = 2.0f * c1;
    float cm2 = 1.0f, cm1 = c1;
    rad[0] = env;
    rad[1] = c1 * env;
    #pragma unroll
    for (int k = 2; k < 8; k++) {
      float c = two_c1 * cm1 - cm2;
      rad[k] = c * env;
      cm2 = cm1; cm1 = c;
    }
  }

  // ---- gather P[dst] via float4 (204 float4s) ----
  {
    const float4* Pn4 = (const float4*)(P + (size_t)d_n * 816);
    float4* sP4 = (float4*)sP;
    sP4[lane] = Pn4[lane];
    sP4[lane + 64] = Pn4[lane + 64];
    sP4[lane + 128] = Pn4[lane + 128];
    if (lane < 12) sP4[lane + 192] = Pn4[lane + 192];
  }

  // ---- q[i*16+r] = sum_k W2[(i*16+r)*8+k] * rad[k], 176 values ----
  #pragma unroll
  for (int p = 0; p < 3; p++) {
    int t = lane + 64 * p;
    if (t < 176) {
      const float4* w = (const float4*)(W2 + t * 8);
      float4 wa = w[0], wb = w[1];
      sq[t] = wa.x * rad[0] + wa.y * rad[1] + wa.z * rad[2] + wa.w * rad[3]
            + wb.x * rad[4] + wb.y * rad[5] + wb.z * rad[6] + wb.w * rad[7];
    }
  }

  // preload Wo_d rows for this lane's channel d (hide latency across barrier)
  int d = lane & 31, h = lane >> 5;
  float4 w0q[4], w1q[4], w2q[4], w3q[4];
  {
    const float4* p0 = (const float4*)(Wo_d + d * 16);
    const float4* p1 = (const float4*)(Wo_d + 512 + d * 16);
    const float4* p2 = (const float4*)(Wo_d + 1024 + d * 16);
    const float4* p3 = (const float4*)(Wo_d + 1536 + d * 16);
    #pragma unroll
    for (int c = 0; c < 4; c++) { w0q[c] = p0[c]; w1q[c] = p1[c]; w2q[c] = p2[c]; w3q[c] = p3[c]; }
  }

  __syncthreads();

  float* Mn = M + (size_t)s_n * 528;

  // ---- scalar messages m_a[k][r] (rank space, 48) ----
  if (lane < 48) {
    int k = lane >> 4, r = lane & 15;
    float val;
    if (k == 0) {                       // tp_000
      val = sP[r] * sq[r];
    } else if (k == 1) {                // tp_110: (pv110 . rv)*q1
      const float* pv = &sP[48 + 48 + 3 * r];
      val = (pv[0] * rv0 + pv[1] * rv1 + pv[2] * rv2) * sq[16 + r];
    } else {                            // tp_220: (rv^T pd220 rv)*q2
      const float* pd = &sP[240 + 288 + 9 * r];
      float a = pd[0] * rv0 + pd[1] * rv1 + pd[2] * rv2;
      float b = pd[3] * rv0 + pd[4] * rv1 + pd[5] * rv2;
      float c = pd[6] * rv0 + pd[7] * rv1 + pd[8] * rv2;
      val = (a * rv0 + b * rv1 + c * rv2) * sq[32 + r];
    }
    atomicAdd(&Mn[lane], val);
  }

  // ---- vector messages m_v[k][r][j] (rank space, 4x48), lane: r=lane>>2, j=lane&3 ----
  {
    int r = lane >> 2, j = lane & 3;
    if (j < 3) {
      int o = r * 3 + j;
      // k0 tp_011: pa011*q3 (x) rv
      atomicAdd(&Mn[48 + o], sP[16 + r] * sq[48 + r] * rva[j]);
      // k1 tp_101: pv101*q4
      atomicAdd(&Mn[96 + o], sP[48 + 3 * r + j] * sq[64 + r]);
      // k2 tp_121: (pv121 . rv)*q5 (x) rv
      const float* pv = &sP[48 + 144 + 3 * r];
      atomicAdd(&Mn[144 + o], (pv[0] * rv0 + pv[1] * rv1 + pv[2] * rv2) * sq[80 + r] * rva[j]);
      // k3 tp_211: q6 * (pd211[i,:] . rv), output index i==j slot
      const float* pd = &sP[240 + 144 + 9 * r + 3 * j];
      atomicAdd(&Mn[192 + o], sq[96 + r] * (pd[0] * rv0 + pd[1] * rv1 + pd[2] * rv2));
    }
  }

  // ---- T intermediates (rank space, repacked r-contiguous) ----
  if (lane < 16) sT0[lane] = sP[32 + lane] * sq[112 + lane];   // pa022*q7
  {
    int r = lane >> 2, i = lane & 3;
    if (i < 3) {
      sT1[i * 16 + r] = sP[48 + 96 + 3 * r + i] * sq[128 + r];           // pv112*q8
      const float* pd = &sP[240 + 432 + 9 * r + 3 * i];
      sT3[i * 16 + r] = sq[160 + r] * (pd[0] * rv0 + pd[1] * rv1 + pd[2] * rv2);  // tp_222 inner
    }
  }
  #pragma unroll
  for (int p = 0; p < 3; p++) {
    int t = lane + 64 * p;
    if (t < 144) {
      int ij = t >> 4, r = t & 15;
      sT2[t] = sP[240 + 9 * r + ij] * sq[144 + r];                       // pd202*q9
    }
  }
  __syncthreads();

  // ---- psi_d[d][ij] (channel space, 288): factored Wo_d application ----
  {
    const float4* t0q = (const float4*)sT0;
    float a0 = 0.0f;
    #pragma unroll
    for (int c = 0; c < 4; c++) a0 += dot4(w0q[c], t0q[c]);

    float a13[3];
    #pragma unroll
    for (int i = 0; i < 3; i++) {
      const float4* t1q = (const float4*)(sT1 + i * 16);
      const float4* t3q = (const float4*)(sT3 + i * 16);
      float acc = 0.0f;
      #pragma unroll
      for (int c = 0; c < 4; c++) acc += dot4(w1q[c], t1q[c]) + dot4(w3q[c], t3q[c]);
      a13[i] = acc;
    }

    for (int ij = h; ij < 9; ij += 2) {
      const float4* t2q = (const float4*)(sT2 + ij * 16);
      float a2 = 0.0f;
      #pragma unroll
      for (int c = 0; c < 4; c++) a2 += dot4(w2q[c], t2q[c]);
      int i = (ij * 11) >> 5;          // ij/3 for ij in [0,9)
      int j = ij - 3 * i;
      float val = a2 + rva[j] * a13[i] + rva[i] * rva[j] * a0;
      atomicAdd(&Mn[240 + d * 9 + ij], val);
    }
  }
}

// ------------------- K3: per-node rank->channel epilogue --------------------
__global__ __launch_bounds__(256) void node_out_kernel(
    const float* __restrict__ M, const float* __restrict__ Wo_a, const float* __restrict__ Wo_v,
    float* __restrict__ out, int N)
{
  int n = blockIdx.x, tid = threadIdx.x;
  __shared__ float sM[528];
  const float* Mn = M + (size_t)n * 528;
  for (int i = tid; i < 528; i += 256) sM[i] = Mn[i];
  __syncthreads();

  const size_t baseA = 0;
  const size_t baseV = (size_t)N * 128;
  const size_t baseD = (size_t)N * 128 + (size_t)N * 192;

  for (int t = tid; t < 608; t += 256) {
    float val; size_t oidx;
    if (t < 128) {                      // B_a[c]
      int c = t; float acc = 0.0f;
      #pragma unroll
      for (int k = 0; k < 3; k++) {
        const float* w = Wo_a + k * 2048 + c * 16;
        const float* m = &sM[16 * k];
        #pragma unroll
        for (int r = 0; r < 16; r++) acc += w[r] * m[r];
      }
      val = acc; oidx = baseA + (size_t)n * 128 + c;
    } else if (t < 320) {               // B_v[d][j]
      int m_ = t - 128; int d = m_ / 3, j = m_ % 3; float acc = 0.0f;
      #pragma unroll
      for (int k = 0; k < 4; k++) {
        const float* w = Wo_v + k * 1024 + d * 16;
        const float* mv = &sM[48 + 48 * k];
        #pragma unroll
        for (int r = 0; r < 16; r++) acc += w[r] * mv[3 * r + j];
      }
      val = acc; oidx = baseV + (size_t)n * 192 + m_;
    } else {                            // B_d passthrough
      int m_ = t - 320;
      val = sM[240 + m_]; oidx = baseD + (size_t)n * 288 + m_;
    }
    out[oidx] = val;
  }
}

// ---------------------------------------------------------------------------
extern "C" void kernel_launch(void* const* d_in, const int* in_sizes, int n_in,
                              void* d_out, int out_size, void* d_ws, size_t ws_size,
                              hipStream_t stream) {
  const float* r_ij = (const float*)d_in[0];
  const float* x_a  = (const float*)d_in[1];
  const float* x_v  = (const float*)d_in[2];
  const float* x_d  = (const float*)d_in[3];
  const float* W1_a = (const float*)d_in[4];
  const float* W1_v = (const float*)d_in[5];
  const float* W1_d = (const float*)d_in[6];
  const float* W2   = (const float*)d_in[7];
  const float* Wo_a = (const float*)d_in[8];
  const float* Wo_v = (const float*)d_in[9];
  const float* Wo_d = (const float*)d_in[10];
  const int*  src   = (const int*)d_in[11];
  const int*  dst   = (const int*)d_in[12];

  const int E = in_sizes[0] / 3;
  const int N = in_sizes[1] / 128;

  float* P = (float*)d_ws;
  float* M = (float*)((char*)d_ws + (size_t)N * 816 * sizeof(float));

  // M must be zeroed every call (ws is poisoned before each launch)
  hipMemsetAsync(M, 0, (size_t)N * 528 * sizeof(float), stream);

  node_proj_kernel<<<N, 256, 0, stream>>>(x_a, x_v, x_d, W1_a, W1_v, W1_d, P);
  edge_kernel<<<E, 64, 0, stream>>>(r_ij, src, dst, P, M, W2, Wo_d);
  node_out_kernel<<<N, 256, 0, stream>>>(M, Wo_a, Wo_v, (float*)d_out, N);
}

// Round 4
// 583.717 us; speedup vs baseline: 2.7964x; 2.7964x over previous
//
#include <hip/hip_runtime.h>
#include <hip/hip_bf16.h>
#include <math.h>

#define PI_F 3.14159265358979323846f
#define R0_F 5.0f

// ---------------------------------------------------------------------------
// ws layout:
//   P[n][816] float : per-node input projections
//     [0,48)    Pa[k*16+r]                 k=0:pa000,1:pa011,2:pa022
//     [48,240)  Pv[48+k*48+3r+i]           k=0:pv101,1:pv110,2:pv112,3:pv121
//     [240,816) Pd[240+k*144+9r+ij]        k=0:pd202,1:pd211,2:pd220,3:pd222
//   counts[N] | offs[N+1] | cursor[N] | eidx[E]   (ints, CSR by src)
// ---------------------------------------------------------------------------

static __device__ __forceinline__ float dot4(float4 a, float4 b) {
  return a.x * b.x + a.y * b.y + a.z * b.z + a.w * b.w;
}

// ------------------- K1: per-node input projections ------------------------
__global__ __launch_bounds__(256) void node_proj_kernel(
    const float* __restrict__ x_a, const float* __restrict__ x_v, const float* __restrict__ x_d,
    const float* __restrict__ W1_a, const float* __restrict__ W1_v, const float* __restrict__ W1_d,
    float* __restrict__ P)
{
  int n = blockIdx.x, tid = threadIdx.x;
  __shared__ float sx[608];  // xa[128] | xv[192] | xd[288]
  {
    const size_t na = (size_t)n * 128, nv = (size_t)n * 192, nd = (size_t)n * 288;
    if (tid < 128) sx[tid] = x_a[na + tid];
    if (tid < 192) sx[128 + tid] = x_v[nv + tid];
    for (int i = tid; i < 288; i += 256) sx[320 + i] = x_d[nd + i];
  }
  __syncthreads();
  float* Pn = P + (size_t)n * 816;
  for (int o = tid; o < 816; o += 256) {
    float acc = 0.0f;
    if (o < 48) {
      int k = o >> 4, r = o & 15;
      const float* w = W1_a + k * 2048 + r * 128;
      for (int c = 0; c < 128; c++) acc += w[c] * sx[c];
    } else if (o < 240) {
      int m = o - 48; int k = m / 48, rr = m % 48, r = rr / 3, i = rr % 3;
      const float* w = W1_v + k * 1024 + r * 64;
      for (int d = 0; d < 64; d++) acc += w[d] * sx[128 + 3 * d + i];
    } else {
      int m = o - 240; int k = m / 144, rr = m % 144, r = rr / 9, ij = rr % 9;
      const float* w = W1_d + k * 512 + r * 32;
      for (int d = 0; d < 32; d++) acc += w[d] * sx[320 + 9 * d + ij];
    }
    Pn[o] = acc;
  }
}

// ------------------- CSR build ---------------------------------------------
__global__ void hist_kernel(const int* __restrict__ src, int* __restrict__ counts, int E) {
  int e = blockIdx.x * 256 + threadIdx.x;
  if (e < E) atomicAdd(&counts[src[e]], 1);
}

__global__ __launch_bounds__(1024) void scan_kernel(
    const int* __restrict__ counts, int* __restrict__ offs, int* __restrict__ cursor,
    int N, int E)
{
  __shared__ int part[1024];
  int tid = threadIdx.x;
  int chunk = (N + 1023) / 1024;
  int lo = tid * chunk, hi = min(lo + chunk, N);
  int s = 0;
  for (int i = lo; i < hi; i++) s += counts[i];
  part[tid] = s;
  __syncthreads();
  for (int off = 1; off < 1024; off <<= 1) {
    int v = (tid >= off) ? part[tid - off] : 0;
    __syncthreads();
    part[tid] += v;
    __syncthreads();
  }
  int run = part[tid] - s;  // exclusive prefix of this thread's chunk
  for (int i = lo; i < hi; i++) { offs[i] = run; cursor[i] = run; run += counts[i]; }
  if (tid == 0) offs[N] = E;
}

__global__ void scatter_kernel(const int* __restrict__ src, int* __restrict__ cursor,
                               int* __restrict__ eidx, int E) {
  int e = blockIdx.x * 256 + threadIdx.x;
  if (e < E) { int p = atomicAdd(&cursor[src[e]], 1); eidx[p] = e; }
}

// ------------------- K2: one wave per node, atomic-free ---------------------
// LDS float map (1280):
//   [0,816)    sP  (gathered P[dst] for current edge)
//   [816,992)  sq  (q[i*16+r], 176)
//   [992,996)  rvtab: rv0,rv1,rv2,1.0
//   [996,1005) outer[ij] = rv_i*rv_j
//   [1008,1264) edge meta float4[64]: (r0,r1,r2, dst-as-float-bits)
// Epilogue reuses [0,960) as ACC:
//   [0,48) A_a[k*16+r]; [48,240) A_v[48+k*48+j*16+r];
//   [240,960) S[240 + s*180 + ij*20 + r]   (row stride 20 breaks bank aliasing)
__global__ __launch_bounds__(64, 3) void node_gather_kernel(
    const float* __restrict__ r_ij, const int* __restrict__ dst,
    const int* __restrict__ offs, const int* __restrict__ eidx,
    const float* __restrict__ Pg, const float* __restrict__ W2,
    const float* __restrict__ Wo_a, const float* __restrict__ Wo_v, const float* __restrict__ Wo_d,
    float* __restrict__ out, int N)
{
  __shared__ __align__(16) float S[1280];
  float4* S4 = (float4*)S;
  const int n = blockIdx.x, lane = threadIdx.x;
  const int off = offs[n], deg = offs[n + 1] - off;

  // ---- per-lane slot constants (V slots p=0..2, D slots p=3..11) ----
  int aP[12], aQ[12], aF[12];
  unsigned typm = 0;  // bit p set => dot3-with-rv form
  #pragma unroll
  for (int p = 0; p < 3; p++) {
    int t = lane + 64 * p;                 // < 192 always
    int k = t / 48, m = t - 48 * k, jj = m >> 4, r = m & 15;
    int q_ = 816 + (3 + k) * 16 + r;       // q3..q6
    int P_, F_;
    if (k == 0)      { P_ = 16 + r;              F_ = 992 + jj; }
    else if (k == 1) { P_ = 48 + 3 * r + jj;     F_ = 995; }
    else if (k == 2) { P_ = 192 + 3 * r;         F_ = 992 + jj; typm |= 1u << p; }
    else             { P_ = 384 + 9 * r + 3 * jj; F_ = 995;     typm |= 1u << p; }
    aP[p] = P_; aQ[p] = q_; aF[p] = F_;
  }
  #pragma unroll
  for (int p = 0; p < 9; p++) {
    int u = lane + 64 * p;                 // < 576 always
    int s = u / 144, m = u - 144 * s, ij = m >> 4, r = m & 15;
    int i = ij / 3, jj = ij - 3 * i;
    int P_, F_, q_;
    if (s == 0)      { P_ = 32 + r;              q_ = 112 + r; F_ = 996 + ij; }
    else if (s == 1) { P_ = 144 + 3 * r + i;     q_ = 128 + r; F_ = 992 + jj; }
    else if (s == 2) { P_ = 240 + 9 * r + ij;    q_ = 144 + r; F_ = 995; }
    else             { P_ = 672 + 9 * r + 3 * i; q_ = 160 + r; F_ = 992 + jj; typm |= 1u << (3 + p); }
    aP[3 + p] = P_; aQ[3 + p] = 816 + q_; aF[3 + p] = F_;
  }
  const int ak = lane >> 4, ar = lane & 15;   // A slot (lane<48)

  // ---- hoist W2 rows for this lane's q slots ----
  float4 wqa[3], wqb[3];
  #pragma unroll
  for (int p = 0; p < 3; p++) {
    int tq = lane + 64 * p; if (tq > 175) tq = 175;
    const float4* w = (const float4*)(W2 + tq * 8);
    wqa[p] = w[0]; wqb[p] = w[1];
  }

  float accA = 0.0f, acc[12];
  #pragma unroll
  for (int p = 0; p < 12; p++) acc[p] = 0.0f;

  float4 pb0 = {}, pb1 = {}, pb2 = {}, pb3 = {};
  const int l3 = 192 + (lane < 12 ? lane : 0);

  for (int base = 0; base < deg; base += 64) {
    int cnt = min(deg - base, 64);
    __syncthreads();
    if (lane < cnt) {
      int e = eidx[off + base + lane];
      float a = r_ij[3 * (size_t)e], b = r_ij[3 * (size_t)e + 1], c = r_ij[3 * (size_t)e + 2];
      S4[252 + lane] = make_float4(a, b, c, __int_as_float(dst[e]));
    }
    __syncthreads();
    // preload edge 0 of this chunk
    {
      float4 me = S4[252];
      if (me.x * me.x + me.y * me.y + me.z * me.z < 5.0f) {
        const float4* Pp = (const float4*)(Pg + (size_t)__float_as_int(me.w) * 816);
        pb0 = Pp[lane]; pb1 = Pp[64 + lane]; pb2 = Pp[128 + lane]; pb3 = Pp[l3];
      }
    }
    for (int t = 0; t < cnt; t++) {
      float4 me = S4[252 + t];
      float r0 = me.x, r1 = me.y, r2 = me.z;
      float rr = r0 * r0 + r1 * r1 + r2 * r2;
      bool live = rr < 5.0f;
      float rv0 = 0, rv1 = 0, rv2 = 0;
      if (live) {
        float x_sq = rr * (1.0f / R0_F);
        float env = 1.0f - x_sq;
        // rv
        float v0 = r0 * (17.0f / R0_F), v1 = r1 * (17.0f / R0_F), v2 = r2 * (17.0f / R0_F);
        float nn = sqrtf(v0 * v0 + v1 * v1 + v2 * v2);
        float sig = 2.0f / (1.0f + __expf(-nn)) - 1.0f;
        float sc = sig / (nn + 1e-6f);
        rv0 = v0 * sc; rv1 = v1 * sc; rv2 = v2 * sc;
        // radial basis: cos(k*th)*env via Chebyshev
        float rad[8];
        {
          float c1 = __cosf(PI_F * sqrtf(x_sq));
          float two_c1 = 2.0f * c1, cm2 = 1.0f, cm1 = c1;
          rad[0] = env; rad[1] = c1 * env;
          #pragma unroll
          for (int k = 2; k < 8; k++) { float c = two_c1 * cm1 - cm2; rad[k] = c * env; cm2 = cm1; cm1 = c; }
        }
        float4 ra = make_float4(rad[0], rad[1], rad[2], rad[3]);
        float4 rb = make_float4(rad[4], rad[5], rad[6], rad[7]);
        // stage sP from prefetch regs
        S4[lane] = pb0; S4[64 + lane] = pb1; S4[128 + lane] = pb2;
        if (lane < 12) S4[192 + lane] = pb3;
        // q values
        S[816 + lane] = dot4(wqa[0], ra) + dot4(wqb[0], rb);
        S[880 + lane] = dot4(wqa[1], ra) + dot4(wqb[1], rb);
        if (lane < 48) S[944 + lane] = dot4(wqa[2], ra) + dot4(wqb[2], rb);
        // tables
        if (lane < 4) S[992 + lane] = (lane == 0) ? rv0 : (lane == 1) ? rv1 : (lane == 2) ? rv2 : 1.0f;
        if (lane >= 4 && lane < 13) {
          int ij = lane - 4, i = ij / 3, j = ij - 3 * i;
          float a = (i == 0) ? rv0 : (i == 1) ? rv1 : rv2;
          float b = (j == 0) ? rv0 : (j == 1) ? rv1 : rv2;
          S[992 + lane] = a * b;   // outer[ij] at 996+ij
        }
      }
      // prefetch next edge's P row (overlaps with accumulation)
      if (t + 1 < cnt) {
        float4 m2 = S4[252 + t + 1];
        if (m2.x * m2.x + m2.y * m2.y + m2.z * m2.z < 5.0f) {
          const float4* Pp = (const float4*)(Pg + (size_t)__float_as_int(m2.w) * 816);
          pb0 = Pp[lane]; pb1 = Pp[64 + lane]; pb2 = Pp[128 + lane]; pb3 = Pp[l3];
        }
      }
      __syncthreads();
      if (live) {
        // A slot
        if (lane < 48) {
          float v;
          if (ak == 0)      v = S[ar] * S[816 + ar];
          else if (ak == 1) v = (S[96 + 3 * ar] * rv0 + S[97 + 3 * ar] * rv1 + S[98 + 3 * ar] * rv2) * S[832 + ar];
          else {
            int b = 528 + 9 * ar;
            float o = (S[b] * rv0 + S[b + 3] * rv1 + S[b + 6] * rv2) * rv0
                    + (S[b + 1] * rv0 + S[b + 4] * rv1 + S[b + 7] * rv2) * rv1
                    + (S[b + 2] * rv0 + S[b + 5] * rv1 + S[b + 8] * rv2) * rv2;
            v = o * S[848 + ar];
          }
          accA += v;
        }
        // V + D slots, unified form
        #pragma unroll
        for (int p = 0; p < 12; p++) {
          float pv;
          if (typm & (1u << p)) pv = S[aP[p]] * rv0 + S[aP[p] + 1] * rv1 + S[aP[p] + 2] * rv2;
          else                  pv = S[aP[p]];
          acc[p] += pv * S[aQ[p]] * S[aF[p]];
        }
      }
      __syncthreads();
    }
  }

  // ---------------- epilogue: rank->channel, write out ----------------
  __syncthreads();
  if (lane < 48) S[lane] = accA;
  #pragma unroll
  for (int p = 0; p < 3; p++) S[48 + lane + 64 * p] = acc[p];
  #pragma unroll
  for (int p = 0; p < 9; p++) {
    int u = lane + 64 * p;
    int s = u / 144, m = u - 144 * s, ij = m >> 4, r = m & 15;
    S[240 + s * 180 + ij * 20 + r] = acc[3 + p];
  }
  __syncthreads();

  const size_t baseV = (size_t)N * 128;
  const size_t baseD = (size_t)N * 320;

  // B_a
  #pragma unroll
  for (int h = 0; h < 2; h++) {
    int c = lane + 64 * h;
    float a_ = 0.0f;
    #pragma unroll
    for (int k = 0; k < 3; k++) {
      const float4* w = (const float4*)(Wo_a + k * 2048 + c * 16);
      const float4* A4 = (const float4*)(&S[k * 16]);
      #pragma unroll
      for (int cc = 0; cc < 4; cc++) a_ += dot4(w[cc], A4[cc]);
    }
    out[(size_t)n * 128 + c] = a_;
  }
  // B_v (d = lane)
  {
    float o0 = 0, o1 = 0, o2 = 0;
    #pragma unroll
    for (int k = 0; k < 4; k++) {
      const float4* w = (const float4*)(Wo_v + k * 1024 + lane * 16);
      float4 w0 = w[0], w1 = w[1], w2 = w[2], w3 = w[3];
      #pragma unroll
      for (int j = 0; j < 3; j++) {
        const float4* A4 = (const float4*)(&S[48 + k * 48 + j * 16]);
        float v = dot4(w0, A4[0]) + dot4(w1, A4[1]) + dot4(w2, A4[2]) + dot4(w3, A4[3]);
        if (j == 0) o0 += v; else if (j == 1) o1 += v; else o2 += v;
      }
    }
    size_t ov = baseV + (size_t)n * 192 + lane * 3;
    out[ov] = o0; out[ov + 1] = o1; out[ov + 2] = o2;
  }
  // B_d
  #pragma unroll
  for (int p = 0; p < 5; p++) {
    int t = lane + 64 * p;
    if (t < 288) {
      int d = t / 9, ij = t - 9 * d;
      float a_ = 0.0f;
      #pragma unroll
      for (int s = 0; s < 4; s++) {
        const float4* w = (const float4*)(Wo_d + s * 512 + d * 16);
        const float4* A4 = (const float4*)(&S[240 + s * 180 + ij * 20]);
        a_ += dot4(w[0], A4[0]) + dot4(w[1], A4[1]) + dot4(w[2], A4[2]) + dot4(w[3], A4[3]);
      }
      out[baseD + (size_t)n * 288 + t] = a_;
    }
  }
}

// ---------------------------------------------------------------------------
extern "C" void kernel_launch(void* const* d_in, const int* in_sizes, int n_in,
                              void* d_out, int out_size, void* d_ws, size_t ws_size,
                              hipStream_t stream) {
  const float* r_ij = (const float*)d_in[0];
  const float* x_a  = (const float*)d_in[1];
  const float* x_v  = (const float*)d_in[2];
  const float* x_d  = (const float*)d_in[3];
  const float* W1_a = (const float*)d_in[4];
  const float* W1_v = (const float*)d_in[5];
  const float* W1_d = (const float*)d_in[6];
  const float* W2   = (const float*)d_in[7];
  const float* Wo_a = (const float*)d_in[8];
  const float* Wo_v = (const float*)d_in[9];
  const float* Wo_d = (const float*)d_in[10];
  const int*  src   = (const int*)d_in[11];
  const int*  dst   = (const int*)d_in[12];

  const int E = in_sizes[0] / 3;
  const int N = in_sizes[1] / 128;

  float* P    = (float*)d_ws;
  int* counts = (int*)(P + (size_t)N * 816);
  int* offs   = counts + N;
  int* cursor = offs + N + 1;
  int* eidx   = cursor + N;

  hipMemsetAsync(counts, 0, sizeof(int) * (size_t)N, stream);

  hist_kernel<<<(E + 255) / 256, 256, 0, stream>>>(src, counts, E);
  scan_kernel<<<1, 1024, 0, stream>>>(counts, offs, cursor, N, E);
  scatter_kernel<<<(E + 255) / 256, 256, 0, stream>>>(src, cursor, eidx, E);
  node_proj_kernel<<<N, 256, 0, stream>>>(x_a, x_v, x_d, W1_a, W1_v, W1_d, P);
  node_gather_kernel<<<N, 64, 0, stream>>>(r_ij, dst, offs, eidx, P, W2,
                                           Wo_a, Wo_v, Wo_d, (float*)d_out, N);
}